// Round 3
// baseline (41.330 us; speedup 1.0000x reference)
//
#include <hip/hip_runtime.h>

// Problem constants: B=16, T=64, N=128, D=512, H=512, O=256, A=18
#define TT 64
#define DD 512
#define HH 512
#define OO 256
#define AA 18
#define ROWS 1024

// ---------------------------------------------------------------------------
// K1: G = obs @ W1, then fused path-GCN layer-1 combine -> U.
// BM=64 rows == exactly one batch (1024 = 16*64), so t = local row and the
// r-1 / r-2 neighbors are always in-tile.
// BN=32, BK=32, 256 threads, micro-tile 4x2, register-prefetch pipeline.
// Grid: (512/32, 1024/64) = (16, 16) = 256 blocks.
// ---------------------------------------------------------------------------
__global__ __launch_bounds__(256) void k1_gemm_combine(
    const float* __restrict__ A, const float* __restrict__ Bm,
    const float* __restrict__ b1, float* __restrict__ U) {
  constexpr int BM = 64, BN = 32, BK = 32;
  __shared__ float As[BK][BM + 4];  // transposed; 68 floats = 272B (16B mult)
  __shared__ float Bs[BK][BN + 8];  // 40 floats = 160B rows (16B mult)
  __shared__ float Gs[BM][BN + 1];

  const int tid = threadIdx.x;
  const int tx = tid & 15, ty = tid >> 4;
  const int col0 = blockIdx.x * BN;
  const int row0 = blockIdx.y * BM;

  const int ar = tid >> 3, ac = tid & 7;     // A-tile: 2 float4 / thread
  const int br = tid >> 3, bc = tid & 7;     // B-tile: 1 float4 / thread

  float4 pa0, pa1, pb;
  float acc[4][2] = {};

#define LOADG(kb)                                                              \
  {                                                                            \
    pa0 = *reinterpret_cast<const float4*>(                                    \
        &A[(size_t)(row0 + ar) * DD + (kb) + ac * 4]);                         \
    pa1 = *reinterpret_cast<const float4*>(                                    \
        &A[(size_t)(row0 + 32 + ar) * DD + (kb) + ac * 4]);                    \
    pb = *reinterpret_cast<const float4*>(                                     \
        &Bm[(size_t)((kb) + br) * HH + col0 + bc * 4]);                        \
  }

#define STOLDS()                                                               \
  {                                                                            \
    As[ac * 4 + 0][ar] = pa0.x; As[ac * 4 + 1][ar] = pa0.y;                    \
    As[ac * 4 + 2][ar] = pa0.z; As[ac * 4 + 3][ar] = pa0.w;                    \
    As[ac * 4 + 0][32 + ar] = pa1.x; As[ac * 4 + 1][32 + ar] = pa1.y;          \
    As[ac * 4 + 2][32 + ar] = pa1.z; As[ac * 4 + 3][32 + ar] = pa1.w;          \
    *reinterpret_cast<float4*>(&Bs[br][bc * 4]) = pb;                          \
  }

#define COMPUTE()                                                              \
  {                                                                            \
    _Pragma("unroll") for (int kk = 0; kk < BK; ++kk) {                        \
      const float4 av = *reinterpret_cast<const float4*>(&As[kk][ty * 4]);     \
      const float2 bv = *reinterpret_cast<const float2*>(&Bs[kk][tx * 2]);     \
      acc[0][0] = fmaf(av.x, bv.x, acc[0][0]);                                 \
      acc[0][1] = fmaf(av.x, bv.y, acc[0][1]);                                 \
      acc[1][0] = fmaf(av.y, bv.x, acc[1][0]);                                 \
      acc[1][1] = fmaf(av.y, bv.y, acc[1][1]);                                 \
      acc[2][0] = fmaf(av.z, bv.x, acc[2][0]);                                 \
      acc[2][1] = fmaf(av.z, bv.y, acc[2][1]);                                 \
      acc[3][0] = fmaf(av.w, bv.x, acc[3][0]);                                 \
      acc[3][1] = fmaf(av.w, bv.y, acc[3][1]);                                 \
    }                                                                          \
  }

  LOADG(0);
  STOLDS();
  __syncthreads();
  for (int kb = BK; kb < DD; kb += BK) {
    LOADG(kb);
    COMPUTE();
    __syncthreads();
    STOLDS();
    __syncthreads();
  }
  COMPUTE();
#undef LOADG
#undef STOLDS
#undef COMPUTE

  // Stage G tile in LDS for the cross-row combine.
  __syncthreads();  // everyone done reading As/Bs region (reuse barrier)
#pragma unroll
  for (int i = 0; i < 4; ++i)
#pragma unroll
    for (int j = 0; j < 2; ++j) Gs[ty * 4 + i][tx * 2 + j] = acc[i][j];
  __syncthreads();

  // Combine: t == local row (tile is one batch).
  const int rr = tid >> 2;            // 0..63
  const int cg = (tid & 3) * 8;       // 8-col group
  const int t = rr;
  const float is6 = 0.4082482904638630f;  // 1/sqrt(6)
  float c0, c1, c2, d1, d2, al, be;
  if (t <= 1) {
    c0 = 0.f; c1 = 0.f; c2 = 1.f; d1 = 0.f; d2 = 0.f; al = 1.f; be = 0.f;
  } else if (t == 2) {
    c0 = 0.f; c1 = 0.5f; c2 = 0.5f; d1 = 0.5f; d2 = 0.5f; al = 0.5f; be = 0.5f;
  } else {
    c0 = (t == 3) ? is6 : (1.f / 3.f);
    c1 = 1.f / 3.f; c2 = is6;
    d1 = is6; d2 = 0.5f;
    al = is6; be = 0.5f;
  }
  const int rm1 = (rr >= 1) ? rr - 1 : 0;
  const int rm2 = (rr >= 2) ? rr - 2 : 0;

  float ub[8];
#pragma unroll
  for (int k = 0; k < 8; ++k) {
    const float gc = Gs[rr][cg + k];
    const float gb = Gs[rm1][cg + k];
    const float ga = Gs[rm2][cg + k];
    const float bb = b1[col0 + cg + k];
    const float h1a = fmaxf(c0 * ga + c1 * gb + c2 * gc + bb, 0.f);
    const float h1b = fmaxf(d1 * gb + d2 * gc + bb, 0.f);
    ub[k] = al * h1a + be * h1b;
  }
  float* up = &U[(size_t)(row0 + rr) * HH + col0 + cg];
  *reinterpret_cast<float4*>(up) = make_float4(ub[0], ub[1], ub[2], ub[3]);
  *reinterpret_cast<float4*>(up + 4) = make_float4(ub[4], ub[5], ub[6], ub[7]);
}

// ---------------------------------------------------------------------------
// K2: tgt = relu(U @ W2 + b2). BM=32, BN=32, BK=32, 256 threads, 2x2 micro.
// Grid: (256/32, 1024/32) = (8, 32) = 256 blocks.
// ---------------------------------------------------------------------------
__global__ __launch_bounds__(256) void k2_gemm_relu(
    const float* __restrict__ A, const float* __restrict__ Bm,
    const float* __restrict__ b2, float* __restrict__ Tg) {
  constexpr int BM = 32, BN = 32, BK = 32;
  __shared__ float As[BK][BM + 4];  // 36 floats = 144B rows (8B mult for b64)
  __shared__ float Bs[BK][BN + 8];  // 40 floats = 160B rows

  const int tid = threadIdx.x;
  const int tx = tid & 15, ty = tid >> 4;
  const int col0 = blockIdx.x * BN;
  const int row0 = blockIdx.y * BM;

  const int ar = tid >> 3, ac = tid & 7;  // 1 float4 / thread each
  float4 pa, pb;
  float acc[2][2] = {};

#define LOADG(kb)                                                              \
  {                                                                            \
    pa = *reinterpret_cast<const float4*>(                                     \
        &A[(size_t)(row0 + ar) * HH + (kb) + ac * 4]);                         \
    pb = *reinterpret_cast<const float4*>(                                     \
        &Bm[(size_t)((kb) + ar) * OO + col0 + ac * 4]);                        \
  }

#define STOLDS()                                                               \
  {                                                                            \
    As[ac * 4 + 0][ar] = pa.x; As[ac * 4 + 1][ar] = pa.y;                      \
    As[ac * 4 + 2][ar] = pa.z; As[ac * 4 + 3][ar] = pa.w;                      \
    *reinterpret_cast<float4*>(&Bs[ar][ac * 4]) = pb;                          \
  }

#define COMPUTE()                                                              \
  {                                                                            \
    _Pragma("unroll") for (int kk = 0; kk < BK; ++kk) {                        \
      const float2 av = *reinterpret_cast<const float2*>(&As[kk][ty * 2]);     \
      const float2 bv = *reinterpret_cast<const float2*>(&Bs[kk][tx * 2]);     \
      acc[0][0] = fmaf(av.x, bv.x, acc[0][0]);                                 \
      acc[0][1] = fmaf(av.x, bv.y, acc[0][1]);                                 \
      acc[1][0] = fmaf(av.y, bv.x, acc[1][0]);                                 \
      acc[1][1] = fmaf(av.y, bv.y, acc[1][1]);                                 \
    }                                                                          \
  }

  LOADG(0);
  STOLDS();
  __syncthreads();
  for (int kb = BK; kb < HH; kb += BK) {
    LOADG(kb);
    COMPUTE();
    __syncthreads();
    STOLDS();
    __syncthreads();
  }
  COMPUTE();
#undef LOADG
#undef STOLDS
#undef COMPUTE

#pragma unroll
  for (int i = 0; i < 2; ++i)
#pragma unroll
    for (int j = 0; j < 2; ++j) {
      const int r = row0 + ty * 2 + i;
      const int c = col0 + tx * 2 + j;
      Tg[(size_t)r * OO + c] = fmaxf(acc[i][j] + b2[c], 0.f);
    }
}

// ---------------------------------------------------------------------------
// K3: out = tgt @ Wl + bl. 8 rows/block, grid 128.
// ---------------------------------------------------------------------------
__global__ __launch_bounds__(256) void k3_head(
    const float* __restrict__ Tg, const float* __restrict__ Wl,
    const float* __restrict__ bl, float* __restrict__ out) {
  __shared__ float sW[OO * AA];   // 18 KiB
  __shared__ float sT[8][OO + 8];

  const int tid = threadIdx.x;
  for (int i = tid; i < OO * AA; i += 256) sW[i] = Wl[i];
  const int r0 = blockIdx.x * 8;
  for (int i = tid; i < 8 * OO; i += 256) {
    const int m = i >> 8, k = i & 255;
    sT[m][k] = Tg[(size_t)(r0 + m) * OO + k];
  }
  __syncthreads();

  if (tid < 8 * AA) {
    const int m = tid / AA;
    const int o = tid - m * AA;
    float s = bl[o];
#pragma unroll 8
    for (int k = 0; k < OO; ++k) s = fmaf(sT[m][k], sW[k * AA + o], s);
    out[(size_t)(r0 + m) * AA + o] = s;
  }
}

extern "C" void kernel_launch(void* const* d_in, const int* in_sizes, int n_in,
                              void* d_out, int out_size, void* d_ws, size_t ws_size,
                              hipStream_t stream) {
  const float* obs = (const float*)d_in[0];   // [1024, 512]
  const float* W1 = (const float*)d_in[4];    // [512, 512]
  const float* b1 = (const float*)d_in[5];    // [512]
  const float* W2 = (const float*)d_in[6];    // [512, 256]
  const float* b2 = (const float*)d_in[7];    // [256]
  const float* Wl = (const float*)d_in[8];    // [256, 18]
  const float* bl = (const float*)d_in[9];    // [18]
  float* out = (float*)d_out;                 // [1024, 18]

  float* U  = (float*)d_ws;                   // 1024x512 = 2 MiB
  float* Tg = U + (size_t)ROWS * HH;          // 1024x256 = 1 MiB

  k1_gemm_combine<<<dim3(HH / 32, ROWS / 64), 256, 0, stream>>>(obs, W1, b1, U);
  k2_gemm_relu<<<dim3(OO / 32, ROWS / 32), 256, 0, stream>>>(U, W2, b2, Tg);
  k3_head<<<ROWS / 8, 256, 0, stream>>>(Tg, Wl, bl, out);
}